// Round 2
// baseline (256.672 us; speedup 1.0000x reference)
//
#include <hip/hip_runtime.h>

namespace {

constexpr int B = 8, C = 64, H = 256, W = 256;
constexpr int HW = H * W;
constexpr int TP = 64;        // pixels per block (one w-tile of a row)
constexpr int TSTRIDE = 68;   // LDS tile row stride in floats (pad for b128 reads)

typedef float v4f __attribute__((ext_vector_type(4)));
typedef _Float16 h2 __attribute__((ext_vector_type(2)));
typedef _Float16 h4 __attribute__((ext_vector_type(4)));

// ---------------------------------------------------------------------------
// Pass A: transpose x_enc [B,C,HW] fp32 -> xt [B,HW,C] fp16.
// Pure register 4x4 transpose — NO LDS (the previous version's LDS write
// pattern was a 32-way bank conflict: bank = 16*(k+cr) mod 32 put all 64
// lanes in 2 banks; ~11x serialization on 16 scalar writes/thread).
// Thread (p4 = t>>4, c4 = t&15) owns a 4ch x 4px block:
//   loads:  4x float4; per instr the 4 p4-groups of a wave each cover a
//           fully-used 64B segment per channel (16 segments, 100% utilized).
//   stores: 4x 8B (h4); per instr the 16 c4-minor lanes cover one
//           contiguous 128B pixel record (4 records per wave instr).
// ---------------------------------------------------------------------------
__global__ __launch_bounds__(256) void transpose_kernel(
    const float* __restrict__ xenc, _Float16* __restrict__ xt)
{
    const int t   = threadIdx.x;
    const int bid = blockIdx.x;         // B * HW/64 = 8192
    const int b   = bid >> 10;
    const int hw0 = (bid & 1023) << 6;
    const int p4  = t >> 4;             // pixel group (4 px)
    const int c4  = t & 15;             // channel group (4 ch)

    const float* src = xenc + (((size_t)(b * C + c4 * 4)) << 16) + hw0 + p4 * 4;
    const v4f v0 = __builtin_nontemporal_load((const v4f*)(src));
    const v4f v1 = __builtin_nontemporal_load((const v4f*)(src + (1 << 16)));
    const v4f v2 = __builtin_nontemporal_load((const v4f*)(src + (2 << 16)));
    const v4f v3 = __builtin_nontemporal_load((const v4f*)(src + (3 << 16)));

    _Float16* dst = xt + (((size_t)(b * HW + hw0 + p4 * 4)) << 6) + c4 * 4;
    #pragma unroll
    for (int i = 0; i < 4; ++i) {
        h4 o;
        o[0] = (_Float16)v0[i];
        o[1] = (_Float16)v1[i];
        o[2] = (_Float16)v2[i];
        o[3] = (_Float16)v3[i];
        __builtin_nontemporal_store(o, (h4*)(dst + (size_t)i * 64));
    }
}

// ---------------------------------------------------------------------------
// Pass B: warp + gather from the fp16 [B,HW,C] copy. One corner = 128B
// contiguous (64 ch * 2B). Half-wave per pixel: lane k in [0,32) holds
// channels 2k,2k+1 (one half2 per corner), fp32 accumulate.
// ---------------------------------------------------------------------------
__global__ __launch_bounds__(256) void warp2_kernel(
    const float* __restrict__ phi,
    const _Float16* __restrict__ xt,
    const float* __restrict__ mm,
    float* __restrict__ out)
{
    __shared__ float tile[64 * TSTRIDE];  // [c][p], zero-filled
    __shared__ float s_w[4][TP];          // compacted weights (m folded in)
    __shared__ int   s_o[4][TP];          // compacted corner offsets (h*W+w)
    __shared__ int   s_p[TP];             // compacted pixel index in tile
    __shared__ int   s_n;                 // number of in-bounds pixels

    const int t   = threadIdx.x;
    const int bid = blockIdx.x;           // 8192
    const int wt  = bid & 3;
    const int h   = (bid >> 2) & (H - 1);
    const int b   = bid >> 10;
    const int w0  = wt * 64;

    // ---- zero the tile ----
    {
        v4f z = {0.f, 0.f, 0.f, 0.f};
        for (int i = t; i < (64 * TSTRIDE) / 4; i += 256)
            *(v4f*)&tile[i * 4] = z;
    }

    // ---- stage 1: wave 0 computes per-pixel params + ballot-compacts ----
    if (t < 64) {
        const int lane = t;
        const int w    = w0 + lane;
        const int hw   = h * W + w;

        const float p0 = phi[(size_t)(b * 2 + 0) * HW + hw];
        const float p1 = phi[(size_t)(b * 2 + 1) * HW + hw];
        const float mv = mm[(size_t)b * HW + hw];

        const float gx = (2.0f * ((float)w + p0)) / (float)(W - 1) - 1.0f + 2.0f * p0;
        const float gy = (2.0f * ((float)h + p1)) / (float)(H - 1) - 1.0f + 2.0f * p1;
        const float ix = (gx + 1.0f) * (0.5f * (float)W) - 0.5f;
        const float iy = (gy + 1.0f) * (0.5f * (float)H) - 0.5f;

        const float x0f = floorf(ix);
        const float y0f = floorf(iy);
        const float fx1 = ix - x0f, fx0 = 1.0f - fx1;
        const float fy1 = iy - y0f, fy0 = 1.0f - fy1;

        const float wm1 = (float)(W - 1), hm1 = (float)(H - 1);
        const int x0 = (int)fminf(fmaxf(x0f,        0.0f), wm1);
        const int x1 = (int)fminf(fmaxf(x0f + 1.0f, 0.0f), wm1);
        const int y0 = (int)fminf(fmaxf(y0f,        0.0f), hm1);
        const int y1 = (int)fminf(fmaxf(y0f + 1.0f, 0.0f), hm1);

        const bool vx0 = (x0f >= 0.0f) && (x0f < (float)W);
        const bool vx1 = (x0f + 1.0f >= 0.0f) && (x0f + 1.0f < (float)W);
        const bool vy0 = (y0f >= 0.0f) && (y0f < (float)H);
        const bool vy1 = (y0f + 1.0f >= 0.0f) && (y0f + 1.0f < (float)H);

        const float w00 = fy0 * fx0 * ((vy0 && vx0) ? mv : 0.0f);
        const float w01 = fy0 * fx1 * ((vy0 && vx1) ? mv : 0.0f);
        const float w10 = fy1 * fx0 * ((vy1 && vx0) ? mv : 0.0f);
        const float w11 = fy1 * fx1 * ((vy1 && vx1) ? mv : 0.0f);

        const bool inb = (w00 + w01 + w10 + w11) != 0.0f;

        const unsigned long long mask = __ballot(inb);
        const int pos = __popcll(mask & ((1ULL << lane) - 1ULL));
        if (inb) {
            s_w[0][pos] = w00;  s_w[1][pos] = w01;
            s_w[2][pos] = w10;  s_w[3][pos] = w11;
            s_o[0][pos] = y0 * W + x0;
            s_o[1][pos] = y0 * W + x1;
            s_o[2][pos] = y1 * W + x0;
            s_o[3][pos] = y1 * W + x1;
            s_p[pos]    = lane;
        }
        if (lane == 0) s_n = __popcll(mask);
    }
    __syncthreads();

    // ---- stage 2: dense 128B gathers; half-wave per in-bounds pixel ----
    {
        const int wv   = t >> 6;          // wave id 0..3
        const int lane = t & 63;
        const int sub  = lane >> 5;       // which pixel of the pair
        const int k    = lane & 31;       // channel pair: channels 2k, 2k+1
        const int n    = s_n;
        const _Float16* __restrict__ xtb = xt + ((size_t)b << 22);  // b*HW*64

        for (int i0 = wv * 2; i0 < n; i0 += 8) {
            const int i = i0 + sub;
            if (i < n) {
                const float w00 = s_w[0][i], w01 = s_w[1][i];
                const float w10 = s_w[2][i], w11 = s_w[3][i];
                const h2 v00 = *(const h2*)(xtb + (((size_t)s_o[0][i]) << 6) + 2 * k);
                const h2 v01 = *(const h2*)(xtb + (((size_t)s_o[1][i]) << 6) + 2 * k);
                const h2 v10 = *(const h2*)(xtb + (((size_t)s_o[2][i]) << 6) + 2 * k);
                const h2 v11 = *(const h2*)(xtb + (((size_t)s_o[3][i]) << 6) + 2 * k);
                const float lo = (float)v00[0] * w00 + (float)v01[0] * w01
                               + (float)v10[0] * w10 + (float)v11[0] * w11;
                const float hi = (float)v00[1] * w00 + (float)v01[1] * w01
                               + (float)v10[1] * w10 + (float)v11[1] * w11;
                const int p = s_p[i];
                tile[(2 * k    ) * TSTRIDE + p] = lo;
                tile[(2 * k + 1) * TSTRIDE + p] = hi;
            }
        }
    }
    __syncthreads();

    // ---- stage 3: transposed store, nontemporal float4 ----
    {
        const size_t obase = (size_t)b * C * HW + (size_t)h * W + w0;
        const int cl = t >> 4;            // 0..15
        const int p4 = (t & 15) * 4;      // 0..60
        #pragma unroll
        for (int pass = 0; pass < 4; ++pass) {
            const int c = pass * 16 + cl;
            v4f v = *(const v4f*)&tile[c * TSTRIDE + p4];
            __builtin_nontemporal_store(v, (v4f*)(out + obase + (size_t)c * HW + p4));
        }
    }
}

// ---------------------------------------------------------------------------
// Fallback: original single-pass kernel (used when workspace is too small).
// ---------------------------------------------------------------------------
__global__ __launch_bounds__(256) void warp_kernel(
    const float* __restrict__ phi,
    const float* __restrict__ xenc,
    const float* __restrict__ mm,
    float* __restrict__ out)
{
    __shared__ float tile[64 * TSTRIDE];
    __shared__ float s_w[4][TP];
    __shared__ int   s_o[4][TP];
    __shared__ int   s_p[TP];
    __shared__ int   s_n;

    const int t   = threadIdx.x;
    const int bid = blockIdx.x;
    const int wt  = bid & 3;
    const int h   = (bid >> 2) & (H - 1);
    const int b   = bid >> 10;
    const int w0  = wt * 64;

    {
        v4f z = {0.f, 0.f, 0.f, 0.f};
        for (int i = t; i < (64 * TSTRIDE) / 4; i += 256)
            *(v4f*)&tile[i * 4] = z;
    }

    if (t < 64) {
        const int lane = t;
        const int w    = w0 + lane;
        const int hw   = h * W + w;

        const float p0 = phi[(size_t)(b * 2 + 0) * HW + hw];
        const float p1 = phi[(size_t)(b * 2 + 1) * HW + hw];
        const float mv = mm[(size_t)b * HW + hw];

        const float gx = (2.0f * ((float)w + p0)) / (float)(W - 1) - 1.0f + 2.0f * p0;
        const float gy = (2.0f * ((float)h + p1)) / (float)(H - 1) - 1.0f + 2.0f * p1;
        const float ix = (gx + 1.0f) * (0.5f * (float)W) - 0.5f;
        const float iy = (gy + 1.0f) * (0.5f * (float)H) - 0.5f;

        const float x0f = floorf(ix);
        const float y0f = floorf(iy);
        const float fx1 = ix - x0f, fx0 = 1.0f - fx1;
        const float fy1 = iy - y0f, fy0 = 1.0f - fy1;

        const float wm1 = (float)(W - 1), hm1 = (float)(H - 1);
        const int x0 = (int)fminf(fmaxf(x0f,        0.0f), wm1);
        const int x1 = (int)fminf(fmaxf(x0f + 1.0f, 0.0f), wm1);
        const int y0 = (int)fminf(fmaxf(y0f,        0.0f), hm1);
        const int y1 = (int)fminf(fmaxf(y0f + 1.0f, 0.0f), hm1);

        const bool vx0 = (x0f >= 0.0f) && (x0f < (float)W);
        const bool vx1 = (x0f + 1.0f >= 0.0f) && (x0f + 1.0f < (float)W);
        const bool vy0 = (y0f >= 0.0f) && (y0f < (float)H);
        const bool vy1 = (y0f + 1.0f >= 0.0f) && (y0f + 1.0f < (float)H);

        const float w00 = fy0 * fx0 * ((vy0 && vx0) ? mv : 0.0f);
        const float w01 = fy0 * fx1 * ((vy0 && vx1) ? mv : 0.0f);
        const float w10 = fy1 * fx0 * ((vy1 && vx0) ? mv : 0.0f);
        const float w11 = fy1 * fx1 * ((vy1 && vx1) ? mv : 0.0f);

        const bool inb = (w00 + w01 + w10 + w11) != 0.0f;

        const unsigned long long mask = __ballot(inb);
        const int pos = __popcll(mask & ((1ULL << lane) - 1ULL));
        if (inb) {
            s_w[0][pos] = w00;  s_w[1][pos] = w01;
            s_w[2][pos] = w10;  s_w[3][pos] = w11;
            s_o[0][pos] = y0 * W + x0;
            s_o[1][pos] = y0 * W + x1;
            s_o[2][pos] = y1 * W + x0;
            s_o[3][pos] = y1 * W + x1;
            s_p[pos]    = lane;
        }
        if (lane == 0) s_n = __popcll(mask);
    }
    __syncthreads();

    {
        const int wv   = t >> 6;
        const int lane = t & 63;
        const int n    = s_n;
        const float* __restrict__ xb = xenc + ((size_t)b * C + lane) * HW;
        for (int i = wv; i < n; i += 4) {
            const float w00 = s_w[0][i], w01 = s_w[1][i];
            const float w10 = s_w[2][i], w11 = s_w[3][i];
            const int o00 = s_o[0][i], o01 = s_o[1][i];
            const int o10 = s_o[2][i], o11 = s_o[3][i];
            const int p   = s_p[i];
            const float v = xb[o00] * w00 + xb[o01] * w01
                          + xb[o10] * w10 + xb[o11] * w11;
            tile[lane * TSTRIDE + p] = v;
        }
    }
    __syncthreads();

    {
        const size_t obase = (size_t)b * C * HW + (size_t)h * W + w0;
        const int cl = t >> 4;
        const int p4 = (t & 15) * 4;
        #pragma unroll
        for (int pass = 0; pass < 4; ++pass) {
            const int c = pass * 16 + cl;
            v4f v = *(const v4f*)&tile[c * TSTRIDE + p4];
            __builtin_nontemporal_store(v, (v4f*)(out + obase + (size_t)c * HW + p4));
        }
    }
}

}  // namespace

extern "C" void kernel_launch(void* const* d_in, const int* in_sizes, int n_in,
                              void* d_out, int out_size, void* d_ws, size_t ws_size,
                              hipStream_t stream) {
    const float* phi  = (const float*)d_in[0];
    const float* xenc = (const float*)d_in[1];
    const float* mm   = (const float*)d_in[2];
    float* out = (float*)d_out;

    const int blocks = B * H * (W / 64);  // 8192
    const size_t xt_bytes = (size_t)B * C * HW * sizeof(_Float16);  // 67.1 MB

    if (d_ws != nullptr && ws_size >= xt_bytes) {
        _Float16* xt = (_Float16*)d_ws;
        transpose_kernel<<<dim3(blocks), dim3(256), 0, stream>>>(xenc, xt);
        warp2_kernel<<<dim3(blocks), dim3(256), 0, stream>>>(phi, xt, mm, out);
    } else {
        warp_kernel<<<dim3(blocks), dim3(256), 0, stream>>>(phi, xenc, mm, out);
    }
}

// Round 3
// 243.837 us; speedup vs baseline: 1.0526x; 1.0526x over previous
//
#include <hip/hip_runtime.h>

namespace {

constexpr int B = 8, C = 64, H = 256, W = 256;
constexpr int HW = H * W;
constexpr int TP = 64;        // pixels per block (one w-tile of a row)
constexpr int TSTRIDE = 68;   // LDS tile row stride in floats (pad for b128 reads)

typedef float v4f __attribute__((ext_vector_type(4)));

// Single-pass kernel. Verified model (rounds 0-2):
//   dur = reset(~160us) + L3 dirty-poison flush tax(~40us) + ideal traffic(~44us)
// Ideal traffic: write 134 MB (compulsory, output re-poisoned each iter) +
// read ~145 MB (phi/m 6 MB + xenc at 128B-line granularity; the scattered
// corners touch ~92% of lines, so full fetch is within ~10% of minimal).
// Two-pass fp16 [HW,C] repacking (R1/R2) paid its own xt round-trip
// (+10-13us) with no gather savings — the L3 already absorbs the gather
// amplification (FETCH == input size). This kernel is at the traffic floor.
__global__ __launch_bounds__(256) void warp_kernel(
    const float* __restrict__ phi,
    const float* __restrict__ xenc,
    const float* __restrict__ mm,
    float* __restrict__ out)
{
    __shared__ float tile[64 * TSTRIDE];  // [c][p], zero-filled
    __shared__ float s_w[4][TP];          // compacted weights (m folded in)
    __shared__ int   s_o[4][TP];          // compacted corner offsets (h*W+w)
    __shared__ int   s_p[TP];             // compacted pixel index in tile
    __shared__ int   s_n;                 // number of in-bounds pixels

    const int t   = threadIdx.x;
    const int bid = blockIdx.x;           // B*H*(W/64) = 8192 blocks
    const int wt  = bid & 3;
    const int h   = (bid >> 2) & (H - 1);
    const int b   = bid >> 10;
    const int w0  = wt * 64;

    // ---- zero the tile (all 256 threads, float4 writes) ----
    {
        v4f z = {0.f, 0.f, 0.f, 0.f};
        for (int i = t; i < (64 * TSTRIDE) / 4; i += 256)
            *(v4f*)&tile[i * 4] = z;
    }

    // ---- stage 1: wave 0 computes per-pixel params + ballot-compacts ----
    if (t < 64) {
        const int lane = t;
        const int w    = w0 + lane;
        const int hw   = h * W + w;

        const float p0 = phi[(size_t)(b * 2 + 0) * HW + hw];
        const float p1 = phi[(size_t)(b * 2 + 1) * HW + hw];
        const float mv = mm[(size_t)b * HW + hw];

        const float gx = (2.0f * ((float)w + p0)) / (float)(W - 1) - 1.0f + 2.0f * p0;
        const float gy = (2.0f * ((float)h + p1)) / (float)(H - 1) - 1.0f + 2.0f * p1;
        const float ix = (gx + 1.0f) * (0.5f * (float)W) - 0.5f;
        const float iy = (gy + 1.0f) * (0.5f * (float)H) - 0.5f;

        const float x0f = floorf(ix);
        const float y0f = floorf(iy);
        const float fx1 = ix - x0f, fx0 = 1.0f - fx1;
        const float fy1 = iy - y0f, fy0 = 1.0f - fy1;

        const float wm1 = (float)(W - 1), hm1 = (float)(H - 1);
        const int x0 = (int)fminf(fmaxf(x0f,        0.0f), wm1);
        const int x1 = (int)fminf(fmaxf(x0f + 1.0f, 0.0f), wm1);
        const int y0 = (int)fminf(fmaxf(y0f,        0.0f), hm1);
        const int y1 = (int)fminf(fmaxf(y0f + 1.0f, 0.0f), hm1);

        const bool vx0 = (x0f >= 0.0f) && (x0f < (float)W);
        const bool vx1 = (x0f + 1.0f >= 0.0f) && (x0f + 1.0f < (float)W);
        const bool vy0 = (y0f >= 0.0f) && (y0f < (float)H);
        const bool vy1 = (y0f + 1.0f >= 0.0f) && (y0f + 1.0f < (float)H);

        const float w00 = fy0 * fx0 * ((vy0 && vx0) ? mv : 0.0f);
        const float w01 = fy0 * fx1 * ((vy0 && vx1) ? mv : 0.0f);
        const float w10 = fy1 * fx0 * ((vy1 && vx0) ? mv : 0.0f);
        const float w11 = fy1 * fx1 * ((vy1 && vx1) ? mv : 0.0f);

        const bool inb = (w00 + w01 + w10 + w11) != 0.0f;

        const unsigned long long mask = __ballot(inb);
        const int pos = __popcll(mask & ((1ULL << lane) - 1ULL));
        if (inb) {
            s_w[0][pos] = w00;  s_w[1][pos] = w01;
            s_w[2][pos] = w10;  s_w[3][pos] = w11;
            s_o[0][pos] = y0 * W + x0;
            s_o[1][pos] = y0 * W + x1;
            s_o[2][pos] = y1 * W + x0;
            s_o[3][pos] = y1 * W + x1;
            s_p[pos]    = lane;
        }
        if (lane == 0) s_n = __popcll(mask);
    }
    __syncthreads();

    // ---- stage 2: dense gathers, one wave per in-bounds pixel ----
    {
        const int wv   = t >> 6;     // wave id 0..3
        const int lane = t & 63;     // channel
        const int n    = s_n;
        const float* __restrict__ xb = xenc + ((size_t)b * C + lane) * HW;
        for (int i = wv; i < n; i += 4) {
            const float w00 = s_w[0][i], w01 = s_w[1][i];
            const float w10 = s_w[2][i], w11 = s_w[3][i];
            const int o00 = s_o[0][i], o01 = s_o[1][i];
            const int o10 = s_o[2][i], o11 = s_o[3][i];
            const int p   = s_p[i];
            const float v = xb[o00] * w00 + xb[o01] * w01
                          + xb[o10] * w10 + xb[o11] * w11;
            tile[lane * TSTRIDE + p] = v;
        }
    }
    __syncthreads();

    // ---- stage 3: transposed store, nontemporal float4 ----
    {
        const size_t obase = (size_t)b * C * HW + (size_t)h * W + w0;
        const int cl = t >> 4;            // 0..15
        const int p4 = (t & 15) * 4;      // 0..60
        #pragma unroll
        for (int pass = 0; pass < 4; ++pass) {
            const int c = pass * 16 + cl;
            v4f v = *(const v4f*)&tile[c * TSTRIDE + p4];
            __builtin_nontemporal_store(v, (v4f*)(out + obase + (size_t)c * HW + p4));
        }
    }
}

}  // namespace

extern "C" void kernel_launch(void* const* d_in, const int* in_sizes, int n_in,
                              void* d_out, int out_size, void* d_ws, size_t ws_size,
                              hipStream_t stream) {
    const float* phi  = (const float*)d_in[0];
    const float* xenc = (const float*)d_in[1];
    const float* mm   = (const float*)d_in[2];
    float* out = (float*)d_out;

    const int blocks = B * H * (W / 64);  // 8192
    warp_kernel<<<dim3(blocks), dim3(256), 0, stream>>>(phi, xenc, mm, out);
}